// Round 15
// baseline (914.134 us; speedup 1.0000x reference)
//
#include <hip/hip_runtime.h>
#include <cfloat>
#include <cmath>
#include <climits>
#include <cstdint>

// Problem constants
#define N_ROWS   32768
#define D_DIM    512
#define K_CODES  4096

#define EPS_GAP  0.008f     // MFMA-path gap below which we re-check via np-emulation
#define CAND_WIN 0.02f      // fp32-screen window that provably contains the np-argmin
#define FLAG_CAP 12000

typedef short s16x8 __attribute__((ext_vector_type(8)));
typedef float f32x4 __attribute__((ext_vector_type(4)));

// ---------------------------------------------------------------------------
// Flat scratch layout in d_out (float indices).
//  out_q zone [0,16777216): emb_hi [0,1048576) emb_lo [1048576,2097152)
//    pmin [2097152,2162688)=2x32768f  pidx16 u16 2x32768 [2162688,2195456)
//    e_norm [2195456,2199552)  flagcnt [2199552]  flaglist [2199553,2211554)
//    (all dead before vq_gather overwrites out_q)
//  out_emb zone [16809985,18907137):
//    fidx u16 32768 -> 16384 floats [16810000,16826384)
//    hist 4096 ints [16826384,16830480)
//    rowpart 32768 f [16830480,16863248)
//    (DISJOINT — round-14 crash was hist/rowpart aliasing fidx rows>=16384;
//     all dead before the final emb memcpy)
// Outputs: out_q[0,16777216) loss[16777216] inds[16777217,16809985)
//          emb[16809985,18907137) perp[18907137]
// ---------------------------------------------------------------------------

__device__ __forceinline__ short f2bf_rne(float x) {
    unsigned u = __float_as_uint(x);
    unsigned r = (u + 0x7fffu + ((u >> 16) & 1u)) >> 16;
    return (short)r;
}
__device__ __forceinline__ float bf2f(short b) {
    return __uint_as_float(((unsigned)(unsigned short)b) << 16);
}

__device__ __forceinline__ void gld16(const short* g, short* l) {
    __builtin_amdgcn_global_load_lds(
        reinterpret_cast<const __attribute__((address_space(1))) unsigned int*>(
            reinterpret_cast<uintptr_t>(g)),
        reinterpret_cast<__attribute__((address_space(3))) unsigned int*>(
            (unsigned int)(reinterpret_cast<uintptr_t>(l))),
        16, 0, 0);
}

// ---------------------------------------------------------------------------
// numpy fp32 pairwise-sum emulation (AVX512/GCC path) -- unchanged, proven.
// ---------------------------------------------------------------------------
__device__ __forceinline__ float np_block128_sq(const float* p) {
    float P[16];
    #pragma unroll
    for (int l = 0; l < 16; ++l) {
        float s0 = __fmul_rn(p[0 * 16 + l], p[0 * 16 + l]);
        float s1 = __fmul_rn(p[1 * 16 + l], p[1 * 16 + l]);
        float s2 = __fmul_rn(p[2 * 16 + l], p[2 * 16 + l]);
        float s3 = __fmul_rn(p[3 * 16 + l], p[3 * 16 + l]);
        float s4 = __fmul_rn(p[4 * 16 + l], p[4 * 16 + l]);
        float s5 = __fmul_rn(p[5 * 16 + l], p[5 * 16 + l]);
        float s6 = __fmul_rn(p[6 * 16 + l], p[6 * 16 + l]);
        float s7 = __fmul_rn(p[7 * 16 + l], p[7 * 16 + l]);
        float a01 = __fadd_rn(s0, s1);
        float a23 = __fadd_rn(s2, s3);
        float a45 = __fadd_rn(s4, s5);
        float a67 = __fadd_rn(s6, s7);
        P[l] = __fadd_rn(__fadd_rn(a01, a23), __fadd_rn(a45, a67));
    }
    float T3[8];
    #pragma unroll
    for (int k = 0; k < 8; ++k) T3[k] = __fadd_rn(P[k], P[k + 8]);
    float T6[4];
    #pragma unroll
    for (int k = 0; k < 4; ++k) T6[k] = __fadd_rn(T3[k], T3[k + 4]);
    return __fadd_rn(__fadd_rn(__fadd_rn(T6[0], T6[1]), T6[2]), T6[3]);
}
__device__ __forceinline__ float np_sum512_sq(const float* p) {
    float B0 = np_block128_sq(p);
    float B1 = np_block128_sq(p + 128);
    float B2 = np_block128_sq(p + 256);
    float B3 = np_block128_sq(p + 384);
    return __fadd_rn(__fadd_rn(B0, B1), __fadd_rn(B2, B3));
}

// ---------------------------------------------------------------------------
// Kernel 0: split fp32 -> bf16 hi/lo for EMB only (lat is reg-staged now).
// ---------------------------------------------------------------------------
__global__ void vq_convert(const float* __restrict__ emb,
                           short* __restrict__ emb_hi, short* __restrict__ emb_lo) {
    int i = blockIdx.x * 256 + threadIdx.x;   // 262144 octets
    size_t base = (size_t)i * 8;
    float4 a = *(const float4*)(emb + base);
    float4 b = *(const float4*)(emb + base + 4);
    float x[8] = {a.x, a.y, a.z, a.w, b.x, b.y, b.z, b.w};
    s16x8 hv, lv;
    #pragma unroll
    for (int j = 0; j < 8; ++j) {
        short h = f2bf_rne(x[j]);
        hv[j] = h;
        lv[j] = f2bf_rne(x[j] - bf2f(h));
    }
    *(s16x8*)(emb_hi + base) = hv;
    *(s16x8*)(emb_lo + base) = lv;
}

// ---------------------------------------------------------------------------
// Kernel 1: emb row norms (fp32), wave per code.
// ---------------------------------------------------------------------------
__global__ void vq_enorm(const float* __restrict__ emb, float* __restrict__ e_norm) {
    int item = blockIdx.x * 4 + (threadIdx.x >> 6);
    int lane = threadIdx.x & 63;
    const float4* s4 = (const float4*)(emb + (size_t)item * D_DIM);
    float4 a = s4[lane];
    float4 b = s4[64 + lane];
    float s = a.x * a.x + a.y * a.y + a.z * a.z + a.w * a.w
            + b.x * b.x + b.y * b.y + b.z * b.z + b.w * b.w;
    #pragma unroll
    for (int off = 32; off > 0; off >>= 1) s += __shfl_down(s, off);
    if (lane == 0) e_norm[item] = s;
}

// ---------------------------------------------------------------------------
// Kernel 2: MFMA split-bf16 distance GEMM. Block = 256 rows x 256 codes,
// grid (128, 2 K-halves). 16 waves (4x4), wave tile 64x64. A reg-staged
// (f32 load -> split -> swizzled ds_write), B via global_load_lds from
// pre-split emb. Per-kt epilogue folds into persistent LDS reduce state.
// ---------------------------------------------------------------------------
__device__ __forceinline__ int kswz(int r) { return (r & 3) ^ ((r >> 2) & 3); }

#define BROWS 256
#define BCOLS 256
#define KHALF 2048
#define BUFS2 32768   // shorts/buffer: Ah 8192 | Al 8192 | Bh 8192 | Bl 8192

__global__ __launch_bounds__(1024, 4)
void vq_argmin_mfma(const float* __restrict__ lat,
                    const short* __restrict__ Bh_g, const short* __restrict__ Bl_g,
                    const float* __restrict__ e_norm,
                    float* __restrict__ pmin, unsigned short* __restrict__ pidx16)
{
    __shared__ short smem[2 * BUFS2];     // 128KB
    __shared__ float pbest_s[4][256];     // [wc][row]
    __shared__ float psec_s[4][256];
    __shared__ int   pidx_s[4][256];

    const int tid = threadIdx.x;
    const int l   = tid & 63;
    const int wid = tid >> 6;      // 0..15
    const int wr  = wid >> 2;      // 0..3 -> rows wr*64..+63
    const int wc  = wid & 3;       // 0..3 -> cols wc*64..+63
    const int l15 = l & 15;
    const int lhi = l >> 4;
    const int row0  = blockIdx.x * BROWS;
    const int kbase = blockIdx.y * KHALF;

    // init persistent reduce state (1024 entries each)
    ((float*)pbest_s)[tid] = FLT_MAX;
    ((float*)psec_s)[tid]  = FLT_MAX;
    ((int*)pidx_s)[tid]    = 0;

    int offA[4], offB[4];
    #pragma unroll
    for (int m = 0; m < 4; ++m) {
        int r = wr * 64 + m * 16 + l15;
        offA[m] = r * 32 + (lhi ^ kswz(r)) * 8;
    }
    #pragma unroll
    for (int n = 0; n < 4; ++n) {
        int c = wc * 64 + n * 16 + l15;
        offB[n] = c * 32 + (lhi ^ kswz(c)) * 8;
    }

    // staging constants
    const int ar = tid >> 2, asl = tid & 3;
    const int achunk = asl ^ kswz(ar);
    const size_t a_base = (size_t)(row0 + ar) * D_DIM + achunk * 8;  // float off
    const int adst = ar * 32 + asl * 8;                              // shorts
    const int br = tid >> 2, bsl = tid & 3;
    const int bchunk = bsl ^ kswz(br);
    const int bdst = tid * 8;

    // prologue: stage step 0 into buf 0
    {
        size_t go = (size_t)(kbase + br) * D_DIM + bchunk * 8;
        gld16(Bh_g + go, smem + 16384 + bdst);
        gld16(Bl_g + go, smem + 24576 + bdst);
        const float* p = lat + a_base;
        float4 f0 = *(const float4*)p;
        float4 f1 = *(const float4*)(p + 4);
        float x[8] = {f0.x, f0.y, f0.z, f0.w, f1.x, f1.y, f1.z, f1.w};
        s16x8 hv, lv;
        #pragma unroll
        for (int j = 0; j < 8; ++j) {
            short h = f2bf_rne(x[j]);
            hv[j] = h;
            lv[j] = f2bf_rne(x[j] - bf2f(h));
        }
        *(s16x8*)(smem + adst) = hv;
        *(s16x8*)(smem + 8192 + adst) = lv;
    }
    __syncthreads();

    f32x4 acc[4][4];
    #pragma unroll
    for (int m = 0; m < 4; ++m)
        #pragma unroll
        for (int n = 0; n < 4; ++n) acc[m][n] = (f32x4){0.f, 0.f, 0.f, 0.f};

    for (int s = 0; s < 128; ++s) {
        short* cur = smem + (s & 1) * BUFS2;
        short* nxt = smem + ((s & 1) ^ 1) * BUFS2;

        float4 nf0, nf1;
        if (s < 127) {
            const int s1 = s + 1;
            const int k0 = (s1 & 15) * 32;
            // A f32 loads to regs (latency hides under MFMA)
            const float* p = lat + a_base + k0;
            nf0 = *(const float4*)p;
            nf1 = *(const float4*)(p + 4);
            // B direct-to-LDS
            size_t go = (size_t)(kbase + (s1 >> 4) * 256 + br) * D_DIM + k0 + bchunk * 8;
            gld16(Bh_g + go, nxt + 16384 + bdst);
            gld16(Bl_g + go, nxt + 24576 + bdst);
        }

        s16x8 ah[4], al[4];
        #pragma unroll
        for (int m = 0; m < 4; ++m) {
            ah[m] = *(const s16x8*)(cur + offA[m]);
            al[m] = *(const s16x8*)(cur + 8192 + offA[m]);
        }
        #pragma unroll
        for (int n = 0; n < 4; ++n) {
            s16x8 bh = *(const s16x8*)(cur + 16384 + offB[n]);
            s16x8 bl = *(const s16x8*)(cur + 24576 + offB[n]);
            #pragma unroll
            for (int m = 0; m < 4; ++m) {
                acc[m][n] = __builtin_amdgcn_mfma_f32_16x16x32_bf16(ah[m], bh, acc[m][n], 0, 0, 0);
                acc[m][n] = __builtin_amdgcn_mfma_f32_16x16x32_bf16(ah[m], bl, acc[m][n], 0, 0, 0);
                acc[m][n] = __builtin_amdgcn_mfma_f32_16x16x32_bf16(al[m], bh, acc[m][n], 0, 0, 0);
            }
        }

        if ((s & 15) == 15) {
            // per-code-tile epilogue: fold into persistent LDS state
            const int cb0 = kbase + (s >> 4) * 256;
            float en[4];
            int   cc[4];
            #pragma unroll
            for (int n = 0; n < 4; ++n) {
                cc[n] = cb0 + wc * 64 + n * 16 + l15;
                en[n] = e_norm[cc[n]];
            }
            #pragma unroll
            for (int m = 0; m < 4; ++m)
                #pragma unroll
                for (int r = 0; r < 4; ++r) {
                    float v = FLT_MAX, sc = FLT_MAX;
                    int ii = 0;
                    #pragma unroll
                    for (int n = 0; n < 4; ++n) {
                        float dv = __fmaf_rn(-2.f, acc[m][n][r], en[n]);
                        if (dv < v) { sc = v; v = dv; ii = cc[n]; }
                        else if (dv < sc) sc = dv;
                    }
                    // reduce over the 16 l15 lanes (columns)
                    #pragma unroll
                    for (int off = 8; off > 0; off >>= 1) {
                        float v2 = __shfl_xor(v, off);
                        float s2 = __shfl_xor(sc, off);
                        int   i2 = __shfl_xor(ii, off);
                        float ns = fminf(fminf(sc, s2), fmaxf(v, v2));
                        if (v2 < v || (v2 == v && i2 < ii)) { v = v2; ii = i2; }
                        sc = ns;
                    }
                    if (l15 == 0) {
                        int rb = wr * 64 + m * 16 + lhi * 4 + r;
                        float ob = pbest_s[wc][rb];
                        float os = psec_s[wc][rb];
                        float nsec = fminf(fminf(os, sc), fmaxf(ob, v));
                        if (v < ob) { pbest_s[wc][rb] = v; pidx_s[wc][rb] = ii; }
                        psec_s[wc][rb] = nsec;
                    }
                }
            #pragma unroll
            for (int m = 0; m < 4; ++m)
                #pragma unroll
                for (int n = 0; n < 4; ++n) acc[m][n] = (f32x4){0.f, 0.f, 0.f, 0.f};
        }

        if (s < 127) {
            // convert + swizzled ds_write of next A tile
            float x[8] = {nf0.x, nf0.y, nf0.z, nf0.w, nf1.x, nf1.y, nf1.z, nf1.w};
            s16x8 hv, lv;
            #pragma unroll
            for (int j = 0; j < 8; ++j) {
                short h = f2bf_rne(x[j]);
                hv[j] = h;
                lv[j] = f2bf_rne(x[j] - bf2f(h));
            }
            *(s16x8*)(nxt + adst) = hv;
            *(s16x8*)(nxt + 8192 + adst) = lv;
        }
        __syncthreads();   // drains gld16 (vmcnt) + ds_writes (lgkmcnt)
    }

    // final merge over the 4 wc waves; write per-half results + flag bit
    if (tid < 256) {
        float B = FLT_MAX, S = FLT_MAX;
        int I = 0;
        #pragma unroll
        for (int w = 0; w < 4; ++w) {
            float b = pbest_s[w][tid], s = psec_s[w][tid];
            int i = pidx_s[w][tid];
            if (b < B || (b == B && i < I)) { S = fminf(B, s); B = b; I = i; }
            else S = fminf(S, fminf(b, s));
        }
        int row = row0 + tid;
        pmin[blockIdx.y * N_ROWS + row] = B;
        unsigned short pk = (unsigned short)I;
        if (S - B < EPS_GAP) pk |= 0x8000;
        pidx16[blockIdx.y * N_ROWS + row] = pk;
    }
}

// ---------------------------------------------------------------------------
// Kernel 2b: merge the two K-halves -> fidx + flag list.
// Proxy flag (half flags | cross-half near-tie) is a superset of the exact
// combined-gap flag.
// ---------------------------------------------------------------------------
__global__ void vq_select(const float* __restrict__ pmin,
                          const unsigned short* __restrict__ pidx16,
                          unsigned short* __restrict__ fidx,
                          int* __restrict__ flagcnt, int* __restrict__ flaglist) {
    int row = blockIdx.x * 256 + threadIdx.x;
    float v0 = pmin[row], v1 = pmin[N_ROWS + row];
    unsigned p0 = pidx16[row], p1 = pidx16[N_ROWS + row];
    int i0 = p0 & 0xFFF, i1 = p1 & 0xFFF;
    int bi = (v1 < v0) ? i1 : i0;   // tie -> half 0 (lower index)
    fidx[row] = (unsigned short)bi;
    bool fl = ((p0 | p1) & 0x8000u) != 0 || fabsf(v0 - v1) < EPS_GAP;
    if (fl) {
        int p = atomicAdd(flagcnt, 1);
        if (p < FLAG_CAP) flaglist[p] = row;
    }
}

// ---------------------------------------------------------------------------
// Kernel 3: flagged-row resolve — one row per block, 16 waves, x2 unroll,
// fp32 screen + bit-exact np eval. (proven in rounds 11-13)
// ---------------------------------------------------------------------------
#define FIXT 1024
#define NWAV 16
#define MAXC 128

__global__ __launch_bounds__(FIXT)
void vq_fixrow(const float* __restrict__ lat, const float* __restrict__ emb,
               const int* __restrict__ flagcnt, const int* __restrict__ flaglist,
               unsigned short* __restrict__ fidx)
{
    __shared__ float xs[D_DIM];
    __shared__ float dall[K_CODES];
    __shared__ float wmin_s[NWAV];
    __shared__ int   ccnt;
    __shared__ int   cands[MAXC];
    __shared__ float cd32[MAXC];

    const int t    = threadIdx.x;
    const int wave = t >> 6;
    const int lane = t & 63;
    int cnt = *flagcnt;
    if (cnt > FLAG_CAP) cnt = FLAG_CAP;

    for (int f = blockIdx.x; f < cnt; f += gridDim.x) {
        const int row = flaglist[f];
        __syncthreads();
        if (t < D_DIM) xs[t] = lat[(size_t)row * D_DIM + t];
        if (t == 0) ccnt = 0;
        __syncthreads();

        float x8[8];
        #pragma unroll
        for (int q = 0; q < 8; ++q) x8[q] = xs[lane * 8 + q];

        float lmin = FLT_MAX;
        for (int c = wave; c < K_CODES; c += 2 * NWAV) {
            const int c2 = c + NWAV;
            const float4* e4a = (const float4*)(emb + (size_t)c  * D_DIM);
            const float4* e4b = (const float4*)(emb + (size_t)c2 * D_DIM);
            float4 ea0 = e4a[lane * 2], ea1 = e4a[lane * 2 + 1];
            float4 eb0 = e4b[lane * 2], eb1 = e4b[lane * 2 + 1];

            float p0 = x8[0] - ea0.x, p1 = x8[1] - ea0.y;
            float p2 = x8[2] - ea0.z, p3 = x8[3] - ea0.w;
            float p4 = x8[4] - ea1.x, p5 = x8[5] - ea1.y;
            float p6 = x8[6] - ea1.z, p7 = x8[7] - ea1.w;
            float sA = __fmaf_rn(p0, p0, __fmaf_rn(p1, p1, __fmaf_rn(p2, p2, p3 * p3)));
            float sB = __fmaf_rn(p4, p4, __fmaf_rn(p5, p5, __fmaf_rn(p6, p6, p7 * p7)));
            float u = sA + sB;

            float q0 = x8[0] - eb0.x, q1 = x8[1] - eb0.y;
            float q2 = x8[2] - eb0.z, q3 = x8[3] - eb0.w;
            float q4 = x8[4] - eb1.x, q5 = x8[5] - eb1.y;
            float q6 = x8[6] - eb1.z, q7 = x8[7] - eb1.w;
            float tA = __fmaf_rn(q0, q0, __fmaf_rn(q1, q1, __fmaf_rn(q2, q2, q3 * q3)));
            float tB = __fmaf_rn(q4, q4, __fmaf_rn(q5, q5, __fmaf_rn(q6, q6, q7 * q7)));
            float v = tA + tB;

            #pragma unroll
            for (int off = 32; off > 0; off >>= 1) {
                u += __shfl_xor(u, off);
                v += __shfl_xor(v, off);
            }
            if (lane == 0) { dall[c] = u; dall[c2] = v; }
            lmin = fminf(lmin, fminf(u, v));
        }
        if (lane == 0) wmin_s[wave] = lmin;
        __syncthreads();

        float gmin = wmin_s[0];
        #pragma unroll
        for (int w = 1; w < NWAV; ++w) gmin = fminf(gmin, wmin_s[w]);
        const float thr = gmin + CAND_WIN;

        for (int c = t; c < K_CODES; c += FIXT) {
            if (dall[c] < thr) {
                int p = atomicAdd(&ccnt, 1);
                if (p < MAXC) cands[p] = c;
            }
        }
        __syncthreads();

        int nc = ccnt < MAXC ? ccnt : MAXC;
        if (t < nc) {
            int c = cands[t];
            const float* e = emb + (size_t)c * D_DIM;
            float t1 = np_sum512_sq(xs);
            float t2 = np_sum512_sq(e);
            float dot = 0.f;
            for (int k = 0; k < D_DIM; ++k)
                dot = __fmaf_rn(xs[k], e[k], dot);     // sequential, BLAS order
            cd32[t] = __fsub_rn(__fadd_rn(t1, t2), __fmul_rn(2.f, dot));
        }
        __syncthreads();

        if (t == 0) {
            float bv = cd32[0]; int bx = cands[0];
            for (int w = 1; w < nc; ++w)
                if (cd32[w] < bv || (cd32[w] == bv && cands[w] < bx)) {
                    bv = cd32[w]; bx = cands[w];
                }
            fidx[row] = (unsigned short)bx;
        }
    }
}

// ---------------------------------------------------------------------------
// Kernel 4: gather quantized rows, per-row MSE partial, histogram.
// ---------------------------------------------------------------------------
__global__ void vq_gather(const float* __restrict__ lat, const float* __restrict__ emb,
                          const unsigned short* __restrict__ fidx,
                          float* __restrict__ out_q,
                          float* __restrict__ rowpart, int* __restrict__ hist) {
    int row  = blockIdx.x * 4 + (threadIdx.x >> 6);
    int lane = threadIdx.x & 63;
    int idx  = fidx[row];

    if (lane == 0) atomicAdd(&hist[idx], 1);

    const float4* e4 = (const float4*)(emb + (size_t)idx * D_DIM);
    const float4* x4 = (const float4*)(lat + (size_t)row * D_DIM);
    float4*       q4 = (float4*)(out_q + (size_t)row * D_DIM);

    float s = 0.f;
    #pragma unroll
    for (int i = 0; i < 2; ++i) {
        float4 e = e4[i * 64 + lane];
        float4 x = x4[i * 64 + lane];
        q4[i * 64 + lane] = e;
        float dx = e.x - x.x, dy = e.y - x.y, dz = e.z - x.z, dw = e.w - x.w;
        s += dx * dx + dy * dy + dz * dz + dw * dw;
    }
    #pragma unroll
    for (int off = 32; off > 0; off >>= 1) s += __shfl_down(s, off);
    if (lane == 0) rowpart[row] = s;
}

// ---------------------------------------------------------------------------
// Kernel 5: final reductions (loss, perplexity).
// ---------------------------------------------------------------------------
__global__ void vq_finalize(const float* __restrict__ rowpart, const int* __restrict__ hist,
                            float* __restrict__ out_loss, float* __restrict__ out_perp) {
    __shared__ float sdata[256];
    int t = threadIdx.x;

    float s = 0.f;
    for (int i = t; i < N_ROWS; i += 256) s += rowpart[i];
    sdata[t] = s;
    __syncthreads();
    for (int st = 128; st > 0; st >>= 1) {
        if (t < st) sdata[t] += sdata[t + st];
        __syncthreads();
    }
    if (t == 0) out_loss[0] = 1.05f * (sdata[0] / ((float)N_ROWS * (float)D_DIM));
    __syncthreads();

    float p = 0.f;
    for (int i = t; i < K_CODES; i += 256) {
        float pr = (float)hist[i] / (float)N_ROWS;
        p += pr * logf(pr + 1e-10f);
    }
    sdata[t] = p;
    __syncthreads();
    for (int st = 128; st > 0; st >>= 1) {
        if (t < st) sdata[t] += sdata[t + st];
        __syncthreads();
    }
    if (t == 0) out_perp[0] = expf(-sdata[0]);
}

// ---------------------------------------------------------------------------
// Kernel 6: fidx u16 -> out_inds float.
// ---------------------------------------------------------------------------
__global__ void vq_inds(const unsigned short* __restrict__ fidx, float* __restrict__ out_inds) {
    int i = blockIdx.x * 1024 + threadIdx.x;
    out_inds[i] = (float)fidx[i];
}

// ---------------------------------------------------------------------------
extern "C" void kernel_launch(void* const* d_in, const int* in_sizes, int n_in,
                              void* d_out, int out_size, void* d_ws, size_t ws_size,
                              hipStream_t stream) {
    const float* lat = (const float*)d_in[0];
    const float* emb = (const float*)d_in[1];
    float* ob = (float*)d_out;

    short* emb_hi = (short*)(ob + 0);
    short* emb_lo = (short*)(ob + 1048576);
    float* pmin   = ob + 2097152;
    unsigned short* pidx16 = (unsigned short*)(ob + 2162688);
    float* e_norm = ob + 2195456;
    int*   flagcnt  = (int*)(ob + 2199552);
    int*   flaglist = (int*)(ob + 2199553);
    unsigned short* fidx = (unsigned short*)(ob + 16810000);  // 16384 floats
    int*   hist    = (int*)(ob + 16826384);                   // past fidx end
    float* rowpart = ob + 16830480;                           // past hist end

    float* out_q    = ob;
    float* out_loss = ob + 16777216;
    float* out_inds = ob + 16777217;
    float* out_emb  = ob + 16809985;
    float* out_perp = ob + 18907137;

    hipMemsetAsync(flagcnt, 0, sizeof(int), stream);
    hipMemsetAsync(hist, 0, K_CODES * sizeof(int), stream);

    vq_convert<<<dim3(1024), dim3(256), 0, stream>>>(emb, emb_hi, emb_lo);
    vq_enorm<<<dim3(1024), dim3(256), 0, stream>>>(emb, e_norm);

    vq_argmin_mfma<<<dim3(N_ROWS / BROWS, 2), dim3(1024), 0, stream>>>(
        lat, emb_hi, emb_lo, e_norm, pmin, pidx16);

    vq_select<<<dim3(N_ROWS / 256), dim3(256), 0, stream>>>(pmin, pidx16,
                                                            fidx, flagcnt, flaglist);

    vq_fixrow<<<dim3(512), dim3(FIXT), 0, stream>>>(lat, emb, flagcnt, flaglist, fidx);

    vq_gather<<<dim3(N_ROWS / 4), dim3(256), 0, stream>>>(lat, emb, fidx, out_q, rowpart, hist);

    vq_finalize<<<dim3(1), dim3(256), 0, stream>>>(rowpart, hist, out_loss, out_perp);

    vq_inds<<<dim3(32), dim3(1024), 0, stream>>>(fidx, out_inds);

    hipMemcpyAsync(out_emb, emb, (size_t)K_CODES * D_DIM * sizeof(float),
                   hipMemcpyDeviceToDevice, stream);
}

// Round 17
// 723.992 us; speedup vs baseline: 1.2626x; 1.2626x over previous
//
#include <hip/hip_runtime.h>
#include <cfloat>
#include <cmath>
#include <climits>
#include <cstdint>

// Problem constants
#define N_ROWS   32768
#define D_DIM    512
#define K_CODES  4096

#define EPS_GAP  0.008f     // MFMA-path gap below which we re-check via np-emulation
#define CAND_WIN 0.02f      // fp32-screen window that provably contains the np-argmin
#define FLAG_CAP 12000

typedef short s16x8 __attribute__((ext_vector_type(8)));
typedef float f32x4 __attribute__((ext_vector_type(4)));

// ---------------------------------------------------------------------------
// Flat scratch layout in d_out (float indices).
//  out_q zone [0,16777216):
//    emb_hi [0,1048576)  emb_lo [1048576,2097152)
//    pmin  2x32768f [2097152,2162688)
//    psec  2x32768f [2162688,2228224)
//    pidx16 u16 2x32768 = 32768 FLOATS [2228224,2260992)   <-- round-16 crash:
//            e_norm/flagcnt/flaglist were placed inside this span; half-1
//            pidx writes trashed flagcnt -> flaglist OOB writes -> page fault.
//    e_norm [2260992,2265088)  flagcnt [2265088]  flaglist [2265089,2277089)
//    (all dead before vq_gather overwrites out_q)
//  out_emb zone [16809985,18907137):
//    fidx u16 32768 -> 16384f [16810000,16826384)
//    hist 4096 ints [16826384,16830480)
//    rowpart 32768f [16830480,16863248)   (disjoint; dead before emb memcpy)
// Outputs: out_q[0,16777216) loss[16777216] inds[16777217,16809985)
//          emb[16809985,18907137) perp[18907137]
// ---------------------------------------------------------------------------

__device__ __forceinline__ short f2bf_rne(float x) {
    unsigned u = __float_as_uint(x);
    unsigned r = (u + 0x7fffu + ((u >> 16) & 1u)) >> 16;
    return (short)r;
}
__device__ __forceinline__ float bf2f(short b) {
    return __uint_as_float(((unsigned)(unsigned short)b) << 16);
}

__device__ __forceinline__ void gld16(const short* g, short* l) {
    __builtin_amdgcn_global_load_lds(
        reinterpret_cast<const __attribute__((address_space(1))) unsigned int*>(
            reinterpret_cast<uintptr_t>(g)),
        reinterpret_cast<__attribute__((address_space(3))) unsigned int*>(
            (unsigned int)(reinterpret_cast<uintptr_t>(l))),
        16, 0, 0);
}

// ---------------------------------------------------------------------------
// numpy fp32 pairwise-sum emulation (AVX512/GCC path) -- unchanged, proven.
// ---------------------------------------------------------------------------
__device__ __forceinline__ float np_block128_sq(const float* p) {
    float P[16];
    #pragma unroll
    for (int l = 0; l < 16; ++l) {
        float s0 = __fmul_rn(p[0 * 16 + l], p[0 * 16 + l]);
        float s1 = __fmul_rn(p[1 * 16 + l], p[1 * 16 + l]);
        float s2 = __fmul_rn(p[2 * 16 + l], p[2 * 16 + l]);
        float s3 = __fmul_rn(p[3 * 16 + l], p[3 * 16 + l]);
        float s4 = __fmul_rn(p[4 * 16 + l], p[4 * 16 + l]);
        float s5 = __fmul_rn(p[5 * 16 + l], p[5 * 16 + l]);
        float s6 = __fmul_rn(p[6 * 16 + l], p[6 * 16 + l]);
        float s7 = __fmul_rn(p[7 * 16 + l], p[7 * 16 + l]);
        float a01 = __fadd_rn(s0, s1);
        float a23 = __fadd_rn(s2, s3);
        float a45 = __fadd_rn(s4, s5);
        float a67 = __fadd_rn(s6, s7);
        P[l] = __fadd_rn(__fadd_rn(a01, a23), __fadd_rn(a45, a67));
    }
    float T3[8];
    #pragma unroll
    for (int k = 0; k < 8; ++k) T3[k] = __fadd_rn(P[k], P[k + 8]);
    float T6[4];
    #pragma unroll
    for (int k = 0; k < 4; ++k) T6[k] = __fadd_rn(T3[k], T3[k + 4]);
    return __fadd_rn(__fadd_rn(__fadd_rn(T6[0], T6[1]), T6[2]), T6[3]);
}
__device__ __forceinline__ float np_sum512_sq(const float* p) {
    float B0 = np_block128_sq(p);
    float B1 = np_block128_sq(p + 128);
    float B2 = np_block128_sq(p + 256);
    float B3 = np_block128_sq(p + 384);
    return __fadd_rn(__fadd_rn(B0, B1), __fadd_rn(B2, B3));
}

// ---------------------------------------------------------------------------
// Kernel 0: split fp32 -> bf16 hi/lo for EMB only.
// ---------------------------------------------------------------------------
__global__ void vq_convert(const float* __restrict__ emb,
                           short* __restrict__ emb_hi, short* __restrict__ emb_lo) {
    int i = blockIdx.x * 256 + threadIdx.x;   // 262144 octets
    size_t base = (size_t)i * 8;
    float4 a = *(const float4*)(emb + base);
    float4 b = *(const float4*)(emb + base + 4);
    float x[8] = {a.x, a.y, a.z, a.w, b.x, b.y, b.z, b.w};
    s16x8 hv, lv;
    #pragma unroll
    for (int j = 0; j < 8; ++j) {
        short h = f2bf_rne(x[j]);
        hv[j] = h;
        lv[j] = f2bf_rne(x[j] - bf2f(h));
    }
    *(s16x8*)(emb_hi + base) = hv;
    *(s16x8*)(emb_lo + base) = lv;
}

// ---------------------------------------------------------------------------
// Kernel 1: emb row norms (fp32), wave per code.
// ---------------------------------------------------------------------------
__global__ void vq_enorm(const float* __restrict__ emb, float* __restrict__ e_norm) {
    int item = blockIdx.x * 4 + (threadIdx.x >> 6);
    int lane = threadIdx.x & 63;
    const float4* s4 = (const float4*)(emb + (size_t)item * D_DIM);
    float4 a = s4[lane];
    float4 b = s4[64 + lane];
    float s = a.x * a.x + a.y * a.y + a.z * a.z + a.w * a.w
            + b.x * b.x + b.y * b.y + b.z * b.z + b.w * b.w;
    #pragma unroll
    for (int off = 32; off > 0; off >>= 1) s += __shfl_down(s, off);
    if (lane == 0) e_norm[item] = s;
}

// ---------------------------------------------------------------------------
// Kernel 2: MFMA split-bf16 distance GEMM. Block = 256 rows x 256 codes,
// grid (128, 2 K-halves). 16 waves (4x4), wave tile 64x64. A reg-staged,
// B via global_load_lds. Final merge writes (pmin, psec, pidx16).
// ---------------------------------------------------------------------------
__device__ __forceinline__ int kswz(int r) { return (r & 3) ^ ((r >> 2) & 3); }

#define BROWS 256
#define BCOLS 256
#define KHALF 2048
#define BUFS2 32768   // shorts/buffer: Ah 8192 | Al 8192 | Bh 8192 | Bl 8192

__global__ __launch_bounds__(1024, 4)
void vq_argmin_mfma(const float* __restrict__ lat,
                    const short* __restrict__ Bh_g, const short* __restrict__ Bl_g,
                    const float* __restrict__ e_norm,
                    float* __restrict__ pmin, float* __restrict__ psec,
                    unsigned short* __restrict__ pidx16)
{
    __shared__ short smem[2 * BUFS2];     // 128KB
    __shared__ float pbest_s[4][256];     // [wc][row]
    __shared__ float psec_s[4][256];
    __shared__ int   pidx_s[4][256];

    const int tid = threadIdx.x;
    const int l   = tid & 63;
    const int wid = tid >> 6;      // 0..15
    const int wr  = wid >> 2;      // 0..3 -> rows wr*64..+63
    const int wc  = wid & 3;       // 0..3 -> cols wc*64..+63
    const int l15 = l & 15;
    const int lhi = l >> 4;
    const int row0  = blockIdx.x * BROWS;
    const int kbase = blockIdx.y * KHALF;

    // init persistent reduce state (1024 entries each)
    ((float*)pbest_s)[tid] = FLT_MAX;
    ((float*)psec_s)[tid]  = FLT_MAX;
    ((int*)pidx_s)[tid]    = 0;

    int offA[4], offB[4];
    #pragma unroll
    for (int m = 0; m < 4; ++m) {
        int r = wr * 64 + m * 16 + l15;
        offA[m] = r * 32 + (lhi ^ kswz(r)) * 8;
    }
    #pragma unroll
    for (int n = 0; n < 4; ++n) {
        int c = wc * 64 + n * 16 + l15;
        offB[n] = c * 32 + (lhi ^ kswz(c)) * 8;
    }

    // staging constants
    const int ar = tid >> 2, asl = tid & 3;
    const int achunk = asl ^ kswz(ar);
    const size_t a_base = (size_t)(row0 + ar) * D_DIM + achunk * 8;  // float off
    const int adst = ar * 32 + asl * 8;                              // shorts
    const int br = tid >> 2, bsl = tid & 3;
    const int bchunk = bsl ^ kswz(br);
    const int bdst = tid * 8;

    // prologue: stage step 0 into buf 0
    {
        size_t go = (size_t)(kbase + br) * D_DIM + bchunk * 8;
        gld16(Bh_g + go, smem + 16384 + bdst);
        gld16(Bl_g + go, smem + 24576 + bdst);
        const float* p = lat + a_base;
        float4 f0 = *(const float4*)p;
        float4 f1 = *(const float4*)(p + 4);
        float x[8] = {f0.x, f0.y, f0.z, f0.w, f1.x, f1.y, f1.z, f1.w};
        s16x8 hv, lv;
        #pragma unroll
        for (int j = 0; j < 8; ++j) {
            short h = f2bf_rne(x[j]);
            hv[j] = h;
            lv[j] = f2bf_rne(x[j] - bf2f(h));
        }
        *(s16x8*)(smem + adst) = hv;
        *(s16x8*)(smem + 8192 + adst) = lv;
    }
    __syncthreads();

    f32x4 acc[4][4];
    #pragma unroll
    for (int m = 0; m < 4; ++m)
        #pragma unroll
        for (int n = 0; n < 4; ++n) acc[m][n] = (f32x4){0.f, 0.f, 0.f, 0.f};

    for (int s = 0; s < 128; ++s) {
        short* cur = smem + (s & 1) * BUFS2;
        short* nxt = smem + ((s & 1) ^ 1) * BUFS2;

        float4 nf0, nf1;
        if (s < 127) {
            const int s1 = s + 1;
            const int k0 = (s1 & 15) * 32;
            const float* p = lat + a_base + k0;
            nf0 = *(const float4*)p;
            nf1 = *(const float4*)(p + 4);
            size_t go = (size_t)(kbase + (s1 >> 4) * 256 + br) * D_DIM + k0 + bchunk * 8;
            gld16(Bh_g + go, nxt + 16384 + bdst);
            gld16(Bl_g + go, nxt + 24576 + bdst);
        }

        s16x8 ah[4], al[4];
        #pragma unroll
        for (int m = 0; m < 4; ++m) {
            ah[m] = *(const s16x8*)(cur + offA[m]);
            al[m] = *(const s16x8*)(cur + 8192 + offA[m]);
        }
        #pragma unroll
        for (int n = 0; n < 4; ++n) {
            s16x8 bh = *(const s16x8*)(cur + 16384 + offB[n]);
            s16x8 bl = *(const s16x8*)(cur + 24576 + offB[n]);
            #pragma unroll
            for (int m = 0; m < 4; ++m) {
                acc[m][n] = __builtin_amdgcn_mfma_f32_16x16x32_bf16(ah[m], bh, acc[m][n], 0, 0, 0);
                acc[m][n] = __builtin_amdgcn_mfma_f32_16x16x32_bf16(ah[m], bl, acc[m][n], 0, 0, 0);
                acc[m][n] = __builtin_amdgcn_mfma_f32_16x16x32_bf16(al[m], bh, acc[m][n], 0, 0, 0);
            }
        }

        if ((s & 15) == 15) {
            // per-code-tile epilogue: fold into persistent LDS state
            const int cb0 = kbase + (s >> 4) * 256;
            float en[4];
            int   cc[4];
            #pragma unroll
            for (int n = 0; n < 4; ++n) {
                cc[n] = cb0 + wc * 64 + n * 16 + l15;
                en[n] = e_norm[cc[n]];
            }
            #pragma unroll
            for (int m = 0; m < 4; ++m)
                #pragma unroll
                for (int r = 0; r < 4; ++r) {
                    float v = FLT_MAX, sc = FLT_MAX;
                    int ii = 0;
                    #pragma unroll
                    for (int n = 0; n < 4; ++n) {
                        float dv = __fmaf_rn(-2.f, acc[m][n][r], en[n]);
                        if (dv < v) { sc = v; v = dv; ii = cc[n]; }
                        else if (dv < sc) sc = dv;
                    }
                    // reduce over the 16 l15 lanes (columns)
                    #pragma unroll
                    for (int off = 8; off > 0; off >>= 1) {
                        float v2 = __shfl_xor(v, off);
                        float s2 = __shfl_xor(sc, off);
                        int   i2 = __shfl_xor(ii, off);
                        float ns = fminf(fminf(sc, s2), fmaxf(v, v2));
                        if (v2 < v || (v2 == v && i2 < ii)) { v = v2; ii = i2; }
                        sc = ns;
                    }
                    if (l15 == 0) {
                        int rb = wr * 64 + m * 16 + lhi * 4 + r;
                        float ob = pbest_s[wc][rb];
                        float os = psec_s[wc][rb];
                        float nsec = fminf(fminf(os, sc), fmaxf(ob, v));
                        if (v < ob) { pbest_s[wc][rb] = v; pidx_s[wc][rb] = ii; }
                        psec_s[wc][rb] = nsec;
                    }
                }
            #pragma unroll
            for (int m = 0; m < 4; ++m)
                #pragma unroll
                for (int n = 0; n < 4; ++n) acc[m][n] = (f32x4){0.f, 0.f, 0.f, 0.f};
        }

        if (s < 127) {
            // convert + swizzled ds_write of next A tile
            float x[8] = {nf0.x, nf0.y, nf0.z, nf0.w, nf1.x, nf1.y, nf1.z, nf1.w};
            s16x8 hv, lv;
            #pragma unroll
            for (int j = 0; j < 8; ++j) {
                short h = f2bf_rne(x[j]);
                hv[j] = h;
                lv[j] = f2bf_rne(x[j] - bf2f(h));
            }
            *(s16x8*)(nxt + adst) = hv;
            *(s16x8*)(nxt + 8192 + adst) = lv;
        }
        __syncthreads();   // drains gld16 (vmcnt) + ds_writes (lgkmcnt)
    }

    // final merge over the 4 wc waves; write per-half (best, sec, idx)
    if (tid < 256) {
        float B = FLT_MAX, S = FLT_MAX;
        int I = 0;
        #pragma unroll
        for (int w = 0; w < 4; ++w) {
            float b = pbest_s[w][tid], s = psec_s[w][tid];
            int i = pidx_s[w][tid];
            if (b < B || (b == B && i < I)) { S = fminf(B, s); B = b; I = i; }
            else S = fminf(S, fminf(b, s));
        }
        int row = row0 + tid;
        pmin[blockIdx.y * N_ROWS + row] = B;
        psec[blockIdx.y * N_ROWS + row] = S;
        pidx16[blockIdx.y * N_ROWS + row] = (unsigned short)I;
    }
}

// ---------------------------------------------------------------------------
// Kernel 2b: EXACT merge of the two K-halves -> fidx + out_inds + flag list.
// Combined second-best of the union: winner half's sec vs loser half's best.
// ---------------------------------------------------------------------------
__global__ void vq_select(const float* __restrict__ pmin, const float* __restrict__ psec,
                          const unsigned short* __restrict__ pidx16,
                          unsigned short* __restrict__ fidx, float* __restrict__ out_inds,
                          int* __restrict__ flagcnt, int* __restrict__ flaglist) {
    int row = blockIdx.x * 256 + threadIdx.x;
    float v0 = pmin[row], v1 = pmin[N_ROWS + row];
    float s0 = psec[row], s1 = psec[N_ROWS + row];
    int   i0 = pidx16[row], i1 = pidx16[N_ROWS + row];

    float best, sec; int bi;
    if (v1 < v0) { best = v1; bi = i1; sec = fminf(s1, v0); }
    else         { best = v0; bi = i0; sec = fminf(s0, v1); }  // tie -> half 0

    fidx[row] = (unsigned short)bi;
    out_inds[row] = (float)bi;
    if (sec - best < EPS_GAP) {
        int p = atomicAdd(flagcnt, 1);
        if (p < FLAG_CAP) flaglist[p] = row;
    }
}

// ---------------------------------------------------------------------------
// Kernel 3: flagged-row resolve — one row per block, 16 waves, x2 unroll,
// fp32 screen + bit-exact np eval. Also writes out_inds for its rows.
// ---------------------------------------------------------------------------
#define FIXT 1024
#define NWAV 16
#define MAXC 128

__global__ __launch_bounds__(FIXT)
void vq_fixrow(const float* __restrict__ lat, const float* __restrict__ emb,
               const int* __restrict__ flagcnt, const int* __restrict__ flaglist,
               unsigned short* __restrict__ fidx, float* __restrict__ out_inds)
{
    __shared__ float xs[D_DIM];
    __shared__ float dall[K_CODES];
    __shared__ float wmin_s[NWAV];
    __shared__ int   ccnt;
    __shared__ int   cands[MAXC];
    __shared__ float cd32[MAXC];

    const int t    = threadIdx.x;
    const int wave = t >> 6;
    const int lane = t & 63;
    int cnt = *flagcnt;
    if (cnt > FLAG_CAP) cnt = FLAG_CAP;

    for (int f = blockIdx.x; f < cnt; f += gridDim.x) {
        const int row = flaglist[f];
        __syncthreads();
        if (t < D_DIM) xs[t] = lat[(size_t)row * D_DIM + t];
        if (t == 0) ccnt = 0;
        __syncthreads();

        float x8[8];
        #pragma unroll
        for (int q = 0; q < 8; ++q) x8[q] = xs[lane * 8 + q];

        float lmin = FLT_MAX;
        for (int c = wave; c < K_CODES; c += 2 * NWAV) {
            const int c2 = c + NWAV;
            const float4* e4a = (const float4*)(emb + (size_t)c  * D_DIM);
            const float4* e4b = (const float4*)(emb + (size_t)c2 * D_DIM);
            float4 ea0 = e4a[lane * 2], ea1 = e4a[lane * 2 + 1];
            float4 eb0 = e4b[lane * 2], eb1 = e4b[lane * 2 + 1];

            float p0 = x8[0] - ea0.x, p1 = x8[1] - ea0.y;
            float p2 = x8[2] - ea0.z, p3 = x8[3] - ea0.w;
            float p4 = x8[4] - ea1.x, p5 = x8[5] - ea1.y;
            float p6 = x8[6] - ea1.z, p7 = x8[7] - ea1.w;
            float sA = __fmaf_rn(p0, p0, __fmaf_rn(p1, p1, __fmaf_rn(p2, p2, p3 * p3)));
            float sB = __fmaf_rn(p4, p4, __fmaf_rn(p5, p5, __fmaf_rn(p6, p6, p7 * p7)));
            float u = sA + sB;

            float q0 = x8[0] - eb0.x, q1 = x8[1] - eb0.y;
            float q2 = x8[2] - eb0.z, q3 = x8[3] - eb0.w;
            float q4 = x8[4] - eb1.x, q5 = x8[5] - eb1.y;
            float q6 = x8[6] - eb1.z, q7 = x8[7] - eb1.w;
            float tA = __fmaf_rn(q0, q0, __fmaf_rn(q1, q1, __fmaf_rn(q2, q2, q3 * q3)));
            float tB = __fmaf_rn(q4, q4, __fmaf_rn(q5, q5, __fmaf_rn(q6, q6, q7 * q7)));
            float v = tA + tB;

            #pragma unroll
            for (int off = 32; off > 0; off >>= 1) {
                u += __shfl_xor(u, off);
                v += __shfl_xor(v, off);
            }
            if (lane == 0) { dall[c] = u; dall[c2] = v; }
            lmin = fminf(lmin, fminf(u, v));
        }
        if (lane == 0) wmin_s[wave] = lmin;
        __syncthreads();

        float gmin = wmin_s[0];
        #pragma unroll
        for (int w = 1; w < NWAV; ++w) gmin = fminf(gmin, wmin_s[w]);
        const float thr = gmin + CAND_WIN;

        for (int c = t; c < K_CODES; c += FIXT) {
            if (dall[c] < thr) {
                int p = atomicAdd(&ccnt, 1);
                if (p < MAXC) cands[p] = c;
            }
        }
        __syncthreads();

        int nc = ccnt < MAXC ? ccnt : MAXC;
        if (t < nc) {
            int c = cands[t];
            const float* e = emb + (size_t)c * D_DIM;
            float t1 = np_sum512_sq(xs);
            float t2 = np_sum512_sq(e);
            float dot = 0.f;
            for (int k = 0; k < D_DIM; ++k)
                dot = __fmaf_rn(xs[k], e[k], dot);     // sequential, BLAS order
            cd32[t] = __fsub_rn(__fadd_rn(t1, t2), __fmul_rn(2.f, dot));
        }
        __syncthreads();

        if (t == 0) {
            float bv = cd32[0]; int bx = cands[0];
            for (int w = 1; w < nc; ++w)
                if (cd32[w] < bv || (cd32[w] == bv && cands[w] < bx)) {
                    bv = cd32[w]; bx = cands[w];
                }
            fidx[row] = (unsigned short)bx;
            out_inds[row] = (float)bx;
        }
    }
}

// ---------------------------------------------------------------------------
// Kernel 4: gather quantized rows, per-row MSE partial, histogram.
// ---------------------------------------------------------------------------
__global__ void vq_gather(const float* __restrict__ lat, const float* __restrict__ emb,
                          const unsigned short* __restrict__ fidx,
                          float* __restrict__ out_q,
                          float* __restrict__ rowpart, int* __restrict__ hist) {
    int row  = blockIdx.x * 4 + (threadIdx.x >> 6);
    int lane = threadIdx.x & 63;
    int idx  = fidx[row];

    if (lane == 0) atomicAdd(&hist[idx], 1);

    const float4* e4 = (const float4*)(emb + (size_t)idx * D_DIM);
    const float4* x4 = (const float4*)(lat + (size_t)row * D_DIM);
    float4*       q4 = (float4*)(out_q + (size_t)row * D_DIM);

    float s = 0.f;
    #pragma unroll
    for (int i = 0; i < 2; ++i) {
        float4 e = e4[i * 64 + lane];
        float4 x = x4[i * 64 + lane];
        q4[i * 64 + lane] = e;
        float dx = e.x - x.x, dy = e.y - x.y, dz = e.z - x.z, dw = e.w - x.w;
        s += dx * dx + dy * dy + dz * dz + dw * dw;
    }
    #pragma unroll
    for (int off = 32; off > 0; off >>= 1) s += __shfl_down(s, off);
    if (lane == 0) rowpart[row] = s;
}

// ---------------------------------------------------------------------------
// Kernel 5: final reductions (loss, perplexity).
// ---------------------------------------------------------------------------
__global__ void vq_finalize(const float* __restrict__ rowpart, const int* __restrict__ hist,
                            float* __restrict__ out_loss, float* __restrict__ out_perp) {
    __shared__ float sdata[256];
    int t = threadIdx.x;

    float s = 0.f;
    for (int i = t; i < N_ROWS; i += 256) s += rowpart[i];
    sdata[t] = s;
    __syncthreads();
    for (int st = 128; st > 0; st >>= 1) {
        if (t < st) sdata[t] += sdata[t + st];
        __syncthreads();
    }
    if (t == 0) out_loss[0] = 1.05f * (sdata[0] / ((float)N_ROWS * (float)D_DIM));
    __syncthreads();

    float p = 0.f;
    for (int i = t; i < K_CODES; i += 256) {
        float pr = (float)hist[i] / (float)N_ROWS;
        p += pr * logf(pr + 1e-10f);
    }
    sdata[t] = p;
    __syncthreads();
    for (int st = 128; st > 0; st >>= 1) {
        if (t < st) sdata[t] += sdata[t + st];
        __syncthreads();
    }
    if (t == 0) out_perp[0] = expf(-sdata[0]);
}

// ---------------------------------------------------------------------------
extern "C" void kernel_launch(void* const* d_in, const int* in_sizes, int n_in,
                              void* d_out, int out_size, void* d_ws, size_t ws_size,
                              hipStream_t stream) {
    const float* lat = (const float*)d_in[0];
    const float* emb = (const float*)d_in[1];
    float* ob = (float*)d_out;

    short* emb_hi = (short*)(ob + 0);
    short* emb_lo = (short*)(ob + 1048576);
    float* pmin   = ob + 2097152;
    float* psec   = ob + 2162688;
    unsigned short* pidx16 = (unsigned short*)(ob + 2228224);  // 32768 floats!
    float* e_norm = ob + 2260992;                              // past pidx16 end
    int*   flagcnt  = (int*)(ob + 2265088);
    int*   flaglist = (int*)(ob + 2265089);
    unsigned short* fidx = (unsigned short*)(ob + 16810000);   // 16384 floats
    int*   hist    = (int*)(ob + 16826384);
    float* rowpart = ob + 16830480;

    float* out_q    = ob;
    float* out_loss = ob + 16777216;
    float* out_inds = ob + 16777217;
    float* out_emb  = ob + 16809985;
    float* out_perp = ob + 18907137;

    hipMemsetAsync(flagcnt, 0, sizeof(int), stream);
    hipMemsetAsync(hist, 0, K_CODES * sizeof(int), stream);

    vq_convert<<<dim3(1024), dim3(256), 0, stream>>>(emb, emb_hi, emb_lo);
    vq_enorm<<<dim3(1024), dim3(256), 0, stream>>>(emb, e_norm);

    vq_argmin_mfma<<<dim3(N_ROWS / BROWS, 2), dim3(1024), 0, stream>>>(
        lat, emb_hi, emb_lo, e_norm, pmin, psec, pidx16);

    vq_select<<<dim3(N_ROWS / 256), dim3(256), 0, stream>>>(pmin, psec, pidx16,
                                                            fidx, out_inds,
                                                            flagcnt, flaglist);

    vq_fixrow<<<dim3(512), dim3(FIXT), 0, stream>>>(lat, emb, flagcnt, flaglist,
                                                    fidx, out_inds);

    vq_gather<<<dim3(N_ROWS / 4), dim3(256), 0, stream>>>(lat, emb, fidx, out_q, rowpart, hist);

    vq_finalize<<<dim3(1), dim3(256), 0, stream>>>(rowpart, hist, out_loss, out_perp);

    hipMemcpyAsync(out_emb, emb, (size_t)K_CODES * D_DIM * sizeof(float),
                   hipMemcpyDeviceToDevice, stream);
}

// Round 18
// 705.897 us; speedup vs baseline: 1.2950x; 1.0256x over previous
//
#include <hip/hip_runtime.h>
#include <cfloat>
#include <cmath>
#include <climits>
#include <cstdint>

// Problem constants
#define N_ROWS   32768
#define D_DIM    512
#define K_CODES  4096

#define EPS_GAP  0.008f     // MFMA-path gap below which we re-check via np-emulation
#define CAND_WIN 0.02f      // fp32-screen window that provably contains the np-argmin
#define FLAG_CAP 12000

typedef short s16x8 __attribute__((ext_vector_type(8)));
typedef float f32x4 __attribute__((ext_vector_type(4)));

// ---------------------------------------------------------------------------
// Flat scratch layout in d_out (float indices).  (identical to round 17)
//  out_q zone [0,16777216):
//    emb_hi [0,1048576)  emb_lo [1048576,2097152)
//    pmin  2x32768f [2097152,2162688)
//    psec  2x32768f [2162688,2228224)
//    pidx16 u16 2x32768 = 32768 FLOATS [2228224,2260992)
//    e_norm [2260992,2265088)  flagcnt [2265088]  flaglist [2265089,2277089)
//  out_emb zone [16809985,18907137):
//    fidx u16 [16810000,16826384) hist [16826384,16830480)
//    rowpart [16830480,16863248)
// Outputs: out_q[0,16777216) loss[16777216] inds[16777217,16809985)
//          emb[16809985,18907137) perp[18907137]
// ---------------------------------------------------------------------------

__device__ __forceinline__ short f2bf_rne(float x) {
    unsigned u = __float_as_uint(x);
    unsigned r = (u + 0x7fffu + ((u >> 16) & 1u)) >> 16;
    return (short)r;
}
__device__ __forceinline__ float bf2f(short b) {
    return __uint_as_float(((unsigned)(unsigned short)b) << 16);
}

__device__ __forceinline__ void gld16(const short* g, short* l) {
    __builtin_amdgcn_global_load_lds(
        reinterpret_cast<const __attribute__((address_space(1))) unsigned int*>(
            reinterpret_cast<uintptr_t>(g)),
        reinterpret_cast<__attribute__((address_space(3))) unsigned int*>(
            (unsigned int)(reinterpret_cast<uintptr_t>(l))),
        16, 0, 0);
}

// ---------------------------------------------------------------------------
// numpy fp32 pairwise-sum emulation (AVX512/GCC path) -- unchanged, proven.
// ---------------------------------------------------------------------------
__device__ __forceinline__ float np_block128_sq(const float* p) {
    float P[16];
    #pragma unroll
    for (int l = 0; l < 16; ++l) {
        float s0 = __fmul_rn(p[0 * 16 + l], p[0 * 16 + l]);
        float s1 = __fmul_rn(p[1 * 16 + l], p[1 * 16 + l]);
        float s2 = __fmul_rn(p[2 * 16 + l], p[2 * 16 + l]);
        float s3 = __fmul_rn(p[3 * 16 + l], p[3 * 16 + l]);
        float s4 = __fmul_rn(p[4 * 16 + l], p[4 * 16 + l]);
        float s5 = __fmul_rn(p[5 * 16 + l], p[5 * 16 + l]);
        float s6 = __fmul_rn(p[6 * 16 + l], p[6 * 16 + l]);
        float s7 = __fmul_rn(p[7 * 16 + l], p[7 * 16 + l]);
        float a01 = __fadd_rn(s0, s1);
        float a23 = __fadd_rn(s2, s3);
        float a45 = __fadd_rn(s4, s5);
        float a67 = __fadd_rn(s6, s7);
        P[l] = __fadd_rn(__fadd_rn(a01, a23), __fadd_rn(a45, a67));
    }
    float T3[8];
    #pragma unroll
    for (int k = 0; k < 8; ++k) T3[k] = __fadd_rn(P[k], P[k + 8]);
    float T6[4];
    #pragma unroll
    for (int k = 0; k < 4; ++k) T6[k] = __fadd_rn(T3[k], T3[k + 4]);
    return __fadd_rn(__fadd_rn(__fadd_rn(T6[0], T6[1]), T6[2]), T6[3]);
}
__device__ __forceinline__ float np_sum512_sq(const float* p) {
    float B0 = np_block128_sq(p);
    float B1 = np_block128_sq(p + 128);
    float B2 = np_block128_sq(p + 256);
    float B3 = np_block128_sq(p + 384);
    return __fadd_rn(__fadd_rn(B0, B1), __fadd_rn(B2, B3));
}

// ---------------------------------------------------------------------------
// Kernel 0 (fused): emb split (RNE hi/lo) + row norms.  Each wave owns
// exactly one emb row (64 octets of 8 floats).
// ---------------------------------------------------------------------------
__global__ void vq_conv_norm(const float* __restrict__ emb,
                             short* __restrict__ emb_hi, short* __restrict__ emb_lo,
                             float* __restrict__ e_norm) {
    int i = blockIdx.x * 256 + threadIdx.x;   // octet index, 262144 total
    int lane = threadIdx.x & 63;
    size_t base = (size_t)i * 8;
    float4 a = *(const float4*)(emb + base);
    float4 b = *(const float4*)(emb + base + 4);
    float x[8] = {a.x, a.y, a.z, a.w, b.x, b.y, b.z, b.w};
    s16x8 hv, lv;
    float s = 0.f;
    #pragma unroll
    for (int j = 0; j < 8; ++j) {
        short h = f2bf_rne(x[j]);
        hv[j] = h;
        lv[j] = f2bf_rne(x[j] - bf2f(h));
        s = __fmaf_rn(x[j], x[j], s);
    }
    *(s16x8*)(emb_hi + base) = hv;
    *(s16x8*)(emb_lo + base) = lv;
    #pragma unroll
    for (int off = 32; off > 0; off >>= 1) s += __shfl_xor(s, off);
    if (lane == 0) e_norm[i >> 6] = s;   // 64 octets per row
}

// ---------------------------------------------------------------------------
// Kernel 2: MFMA split-bf16 distance GEMM. Block = 256 rows x 256 codes,
// grid (128, 2 K-halves). 16 waves (4x4), wave tile 64x64. A reg-staged
// with cheap TRUNCATION split (hi = bits>>16; residual Sterbenz-exact;
// lo = bits(resid)>>16) -- dropped xl*el term <= ~2e-4, far under EPS.
// B via global_load_lds from RNE-split emb. s_setprio around MFMA cluster.
// ---------------------------------------------------------------------------
__device__ __forceinline__ int kswz(int r) { return (r & 3) ^ ((r >> 2) & 3); }

#define BROWS 256
#define BCOLS 256
#define KHALF 2048
#define BUFS2 32768   // shorts/buffer: Ah 8192 | Al 8192 | Bh 8192 | Bl 8192

__device__ __forceinline__ void trunc_split8(const float* x, s16x8* hv, s16x8* lv) {
    #pragma unroll
    for (int j = 0; j < 8; ++j) {
        unsigned ux = __float_as_uint(x[j]);
        short h = (short)(ux >> 16);
        (*hv)[j] = h;
        float r = x[j] - bf2f(h);            // exact (Sterbenz)
        (*lv)[j] = (short)(__float_as_uint(r) >> 16);
    }
}

__global__ __launch_bounds__(1024, 4)
void vq_argmin_mfma(const float* __restrict__ lat,
                    const short* __restrict__ Bh_g, const short* __restrict__ Bl_g,
                    const float* __restrict__ e_norm,
                    float* __restrict__ pmin, float* __restrict__ psec,
                    unsigned short* __restrict__ pidx16)
{
    __shared__ short smem[2 * BUFS2];     // 128KB
    __shared__ float pbest_s[4][256];     // [wc][row]
    __shared__ float psec_s[4][256];
    __shared__ int   pidx_s[4][256];

    const int tid = threadIdx.x;
    const int l   = tid & 63;
    const int wid = tid >> 6;      // 0..15
    const int wr  = wid >> 2;      // 0..3 -> rows wr*64..+63
    const int wc  = wid & 3;       // 0..3 -> cols wc*64..+63
    const int l15 = l & 15;
    const int lhi = l >> 4;
    const int row0  = blockIdx.x * BROWS;
    const int kbase = blockIdx.y * KHALF;

    // init persistent reduce state (1024 entries each)
    ((float*)pbest_s)[tid] = FLT_MAX;
    ((float*)psec_s)[tid]  = FLT_MAX;
    ((int*)pidx_s)[tid]    = 0;

    int offA[4], offB[4];
    #pragma unroll
    for (int m = 0; m < 4; ++m) {
        int r = wr * 64 + m * 16 + l15;
        offA[m] = r * 32 + (lhi ^ kswz(r)) * 8;
    }
    #pragma unroll
    for (int n = 0; n < 4; ++n) {
        int c = wc * 64 + n * 16 + l15;
        offB[n] = c * 32 + (lhi ^ kswz(c)) * 8;
    }

    // staging constants
    const int ar = tid >> 2, asl = tid & 3;
    const int achunk = asl ^ kswz(ar);
    const size_t a_base = (size_t)(row0 + ar) * D_DIM + achunk * 8;  // float off
    const int adst = ar * 32 + asl * 8;                              // shorts
    const int br = tid >> 2, bsl = tid & 3;
    const int bchunk = bsl ^ kswz(br);
    const int bdst = tid * 8;

    // prologue: stage step 0 into buf 0
    {
        size_t go = (size_t)(kbase + br) * D_DIM + bchunk * 8;
        gld16(Bh_g + go, smem + 16384 + bdst);
        gld16(Bl_g + go, smem + 24576 + bdst);
        const float* p = lat + a_base;
        float4 f0 = *(const float4*)p;
        float4 f1 = *(const float4*)(p + 4);
        float x[8] = {f0.x, f0.y, f0.z, f0.w, f1.x, f1.y, f1.z, f1.w};
        s16x8 hv, lv;
        trunc_split8(x, &hv, &lv);
        *(s16x8*)(smem + adst) = hv;
        *(s16x8*)(smem + 8192 + adst) = lv;
    }
    __syncthreads();

    f32x4 acc[4][4];
    #pragma unroll
    for (int m = 0; m < 4; ++m)
        #pragma unroll
        for (int n = 0; n < 4; ++n) acc[m][n] = (f32x4){0.f, 0.f, 0.f, 0.f};

    for (int s = 0; s < 128; ++s) {
        short* cur = smem + (s & 1) * BUFS2;
        short* nxt = smem + ((s & 1) ^ 1) * BUFS2;

        float4 nf0, nf1;
        if (s < 127) {
            const int s1 = s + 1;
            const int k0 = (s1 & 15) * 32;
            const float* p = lat + a_base + k0;
            nf0 = *(const float4*)p;
            nf1 = *(const float4*)(p + 4);
            size_t go = (size_t)(kbase + (s1 >> 4) * 256 + br) * D_DIM + k0 + bchunk * 8;
            gld16(Bh_g + go, nxt + 16384 + bdst);
            gld16(Bl_g + go, nxt + 24576 + bdst);
        }

        s16x8 ah[4], al[4];
        #pragma unroll
        for (int m = 0; m < 4; ++m) {
            ah[m] = *(const s16x8*)(cur + offA[m]);
            al[m] = *(const s16x8*)(cur + 8192 + offA[m]);
        }
        __builtin_amdgcn_s_setprio(1);
        #pragma unroll
        for (int n = 0; n < 4; ++n) {
            s16x8 bh = *(const s16x8*)(cur + 16384 + offB[n]);
            s16x8 bl = *(const s16x8*)(cur + 24576 + offB[n]);
            #pragma unroll
            for (int m = 0; m < 4; ++m) {
                acc[m][n] = __builtin_amdgcn_mfma_f32_16x16x32_bf16(ah[m], bh, acc[m][n], 0, 0, 0);
                acc[m][n] = __builtin_amdgcn_mfma_f32_16x16x32_bf16(ah[m], bl, acc[m][n], 0, 0, 0);
                acc[m][n] = __builtin_amdgcn_mfma_f32_16x16x32_bf16(al[m], bh, acc[m][n], 0, 0, 0);
            }
        }
        __builtin_amdgcn_s_setprio(0);

        if ((s & 15) == 15) {
            // per-code-tile epilogue: fold into persistent LDS state
            const int cb0 = kbase + (s >> 4) * 256;
            float en[4];
            int   cc[4];
            #pragma unroll
            for (int n = 0; n < 4; ++n) {
                cc[n] = cb0 + wc * 64 + n * 16 + l15;
                en[n] = e_norm[cc[n]];
            }
            #pragma unroll
            for (int m = 0; m < 4; ++m)
                #pragma unroll
                for (int r = 0; r < 4; ++r) {
                    float v = FLT_MAX, sc = FLT_MAX;
                    int ii = 0;
                    #pragma unroll
                    for (int n = 0; n < 4; ++n) {
                        float dv = __fmaf_rn(-2.f, acc[m][n][r], en[n]);
                        if (dv < v) { sc = v; v = dv; ii = cc[n]; }
                        else if (dv < sc) sc = dv;
                    }
                    // reduce over the 16 l15 lanes (columns)
                    #pragma unroll
                    for (int off = 8; off > 0; off >>= 1) {
                        float v2 = __shfl_xor(v, off);
                        float s2 = __shfl_xor(sc, off);
                        int   i2 = __shfl_xor(ii, off);
                        float ns = fminf(fminf(sc, s2), fmaxf(v, v2));
                        if (v2 < v || (v2 == v && i2 < ii)) { v = v2; ii = i2; }
                        sc = ns;
                    }
                    if (l15 == 0) {
                        int rb = wr * 64 + m * 16 + lhi * 4 + r;
                        float ob = pbest_s[wc][rb];
                        float os = psec_s[wc][rb];
                        float nsec = fminf(fminf(os, sc), fmaxf(ob, v));
                        if (v < ob) { pbest_s[wc][rb] = v; pidx_s[wc][rb] = ii; }
                        psec_s[wc][rb] = nsec;
                    }
                }
            #pragma unroll
            for (int m = 0; m < 4; ++m)
                #pragma unroll
                for (int n = 0; n < 4; ++n) acc[m][n] = (f32x4){0.f, 0.f, 0.f, 0.f};
        }

        if (s < 127) {
            // truncation split + swizzled ds_write of next A tile
            float x[8] = {nf0.x, nf0.y, nf0.z, nf0.w, nf1.x, nf1.y, nf1.z, nf1.w};
            s16x8 hv, lv;
            trunc_split8(x, &hv, &lv);
            *(s16x8*)(nxt + adst) = hv;
            *(s16x8*)(nxt + 8192 + adst) = lv;
        }
        __syncthreads();   // drains gld16 (vmcnt) + ds_writes (lgkmcnt)
    }

    // final merge over the 4 wc waves; write per-half (best, sec, idx)
    if (tid < 256) {
        float B = FLT_MAX, S = FLT_MAX;
        int I = 0;
        #pragma unroll
        for (int w = 0; w < 4; ++w) {
            float b = pbest_s[w][tid], s = psec_s[w][tid];
            int i = pidx_s[w][tid];
            if (b < B || (b == B && i < I)) { S = fminf(B, s); B = b; I = i; }
            else S = fminf(S, fminf(b, s));
        }
        int row = row0 + tid;
        pmin[blockIdx.y * N_ROWS + row] = B;
        psec[blockIdx.y * N_ROWS + row] = S;
        pidx16[blockIdx.y * N_ROWS + row] = (unsigned short)I;
    }
}

// ---------------------------------------------------------------------------
// Kernel 2b: EXACT merge of the two K-halves -> fidx + out_inds + flag list.
// ---------------------------------------------------------------------------
__global__ void vq_select(const float* __restrict__ pmin, const float* __restrict__ psec,
                          const unsigned short* __restrict__ pidx16,
                          unsigned short* __restrict__ fidx, float* __restrict__ out_inds,
                          int* __restrict__ flagcnt, int* __restrict__ flaglist) {
    int row = blockIdx.x * 256 + threadIdx.x;
    float v0 = pmin[row], v1 = pmin[N_ROWS + row];
    float s0 = psec[row], s1 = psec[N_ROWS + row];
    int   i0 = pidx16[row], i1 = pidx16[N_ROWS + row];

    float best, sec; int bi;
    if (v1 < v0) { best = v1; bi = i1; sec = fminf(s1, v0); }
    else         { best = v0; bi = i0; sec = fminf(s0, v1); }  // tie -> half 0

    fidx[row] = (unsigned short)bi;
    out_inds[row] = (float)bi;
    if (sec - best < EPS_GAP) {
        int p = atomicAdd(flagcnt, 1);
        if (p < FLAG_CAP) flaglist[p] = row;
    }
}

// ---------------------------------------------------------------------------
// Kernel 3: flagged-row resolve — one row per block, 16 waves, x2 unroll,
// fp32 screen + bit-exact np eval. Also writes out_inds for its rows.
// ---------------------------------------------------------------------------
#define FIXT 1024
#define NWAV 16
#define MAXC 128

__global__ __launch_bounds__(FIXT)
void vq_fixrow(const float* __restrict__ lat, const float* __restrict__ emb,
               const int* __restrict__ flagcnt, const int* __restrict__ flaglist,
               unsigned short* __restrict__ fidx, float* __restrict__ out_inds)
{
    __shared__ float xs[D_DIM];
    __shared__ float dall[K_CODES];
    __shared__ float wmin_s[NWAV];
    __shared__ int   ccnt;
    __shared__ int   cands[MAXC];
    __shared__ float cd32[MAXC];

    const int t    = threadIdx.x;
    const int wave = t >> 6;
    const int lane = t & 63;
    int cnt = *flagcnt;
    if (cnt > FLAG_CAP) cnt = FLAG_CAP;

    for (int f = blockIdx.x; f < cnt; f += gridDim.x) {
        const int row = flaglist[f];
        __syncthreads();
        if (t < D_DIM) xs[t] = lat[(size_t)row * D_DIM + t];
        if (t == 0) ccnt = 0;
        __syncthreads();

        float x8[8];
        #pragma unroll
        for (int q = 0; q < 8; ++q) x8[q] = xs[lane * 8 + q];

        float lmin = FLT_MAX;
        for (int c = wave; c < K_CODES; c += 2 * NWAV) {
            const int c2 = c + NWAV;
            const float4* e4a = (const float4*)(emb + (size_t)c  * D_DIM);
            const float4* e4b = (const float4*)(emb + (size_t)c2 * D_DIM);
            float4 ea0 = e4a[lane * 2], ea1 = e4a[lane * 2 + 1];
            float4 eb0 = e4b[lane * 2], eb1 = e4b[lane * 2 + 1];

            float p0 = x8[0] - ea0.x, p1 = x8[1] - ea0.y;
            float p2 = x8[2] - ea0.z, p3 = x8[3] - ea0.w;
            float p4 = x8[4] - ea1.x, p5 = x8[5] - ea1.y;
            float p6 = x8[6] - ea1.z, p7 = x8[7] - ea1.w;
            float sA = __fmaf_rn(p0, p0, __fmaf_rn(p1, p1, __fmaf_rn(p2, p2, p3 * p3)));
            float sB = __fmaf_rn(p4, p4, __fmaf_rn(p5, p5, __fmaf_rn(p6, p6, p7 * p7)));
            float u = sA + sB;

            float q0 = x8[0] - eb0.x, q1 = x8[1] - eb0.y;
            float q2 = x8[2] - eb0.z, q3 = x8[3] - eb0.w;
            float q4 = x8[4] - eb1.x, q5 = x8[5] - eb1.y;
            float q6 = x8[6] - eb1.z, q7 = x8[7] - eb1.w;
            float tA = __fmaf_rn(q0, q0, __fmaf_rn(q1, q1, __fmaf_rn(q2, q2, q3 * q3)));
            float tB = __fmaf_rn(q4, q4, __fmaf_rn(q5, q5, __fmaf_rn(q6, q6, q7 * q7)));
            float v = tA + tB;

            #pragma unroll
            for (int off = 32; off > 0; off >>= 1) {
                u += __shfl_xor(u, off);
                v += __shfl_xor(v, off);
            }
            if (lane == 0) { dall[c] = u; dall[c2] = v; }
            lmin = fminf(lmin, fminf(u, v));
        }
        if (lane == 0) wmin_s[wave] = lmin;
        __syncthreads();

        float gmin = wmin_s[0];
        #pragma unroll
        for (int w = 1; w < NWAV; ++w) gmin = fminf(gmin, wmin_s[w]);
        const float thr = gmin + CAND_WIN;

        for (int c = t; c < K_CODES; c += FIXT) {
            if (dall[c] < thr) {
                int p = atomicAdd(&ccnt, 1);
                if (p < MAXC) cands[p] = c;
            }
        }
        __syncthreads();

        int nc = ccnt < MAXC ? ccnt : MAXC;
        if (t < nc) {
            int c = cands[t];
            const float* e = emb + (size_t)c * D_DIM;
            float t1 = np_sum512_sq(xs);
            float t2 = np_sum512_sq(e);
            float dot = 0.f;
            for (int k = 0; k < D_DIM; ++k)
                dot = __fmaf_rn(xs[k], e[k], dot);     // sequential, BLAS order
            cd32[t] = __fsub_rn(__fadd_rn(t1, t2), __fmul_rn(2.f, dot));
        }
        __syncthreads();

        if (t == 0) {
            float bv = cd32[0]; int bx = cands[0];
            for (int w = 1; w < nc; ++w)
                if (cd32[w] < bv || (cd32[w] == bv && cands[w] < bx)) {
                    bv = cd32[w]; bx = cands[w];
                }
            fidx[row] = (unsigned short)bx;
            out_inds[row] = (float)bx;
        }
    }
}

// ---------------------------------------------------------------------------
// Kernel 4: gather quantized rows, per-row MSE partial, histogram.
// ---------------------------------------------------------------------------
__global__ void vq_gather(const float* __restrict__ lat, const float* __restrict__ emb,
                          const unsigned short* __restrict__ fidx,
                          float* __restrict__ out_q,
                          float* __restrict__ rowpart, int* __restrict__ hist) {
    int row  = blockIdx.x * 4 + (threadIdx.x >> 6);
    int lane = threadIdx.x & 63;
    int idx  = fidx[row];

    if (lane == 0) atomicAdd(&hist[idx], 1);

    const float4* e4 = (const float4*)(emb + (size_t)idx * D_DIM);
    const float4* x4 = (const float4*)(lat + (size_t)row * D_DIM);
    float4*       q4 = (float4*)(out_q + (size_t)row * D_DIM);

    float s = 0.f;
    #pragma unroll
    for (int i = 0; i < 2; ++i) {
        float4 e = e4[i * 64 + lane];
        float4 x = x4[i * 64 + lane];
        q4[i * 64 + lane] = e;
        float dx = e.x - x.x, dy = e.y - x.y, dz = e.z - x.z, dw = e.w - x.w;
        s += dx * dx + dy * dy + dz * dz + dw * dw;
    }
    #pragma unroll
    for (int off = 32; off > 0; off >>= 1) s += __shfl_down(s, off);
    if (lane == 0) rowpart[row] = s;
}

// ---------------------------------------------------------------------------
// Kernel 5: final reductions (loss, perplexity).
// ---------------------------------------------------------------------------
__global__ void vq_finalize(const float* __restrict__ rowpart, const int* __restrict__ hist,
                            float* __restrict__ out_loss, float* __restrict__ out_perp) {
    __shared__ float sdata[256];
    int t = threadIdx.x;

    float s = 0.f;
    for (int i = t; i < N_ROWS; i += 256) s += rowpart[i];
    sdata[t] = s;
    __syncthreads();
    for (int st = 128; st > 0; st >>= 1) {
        if (t < st) sdata[t] += sdata[t + st];
        __syncthreads();
    }
    if (t == 0) out_loss[0] = 1.05f * (sdata[0] / ((float)N_ROWS * (float)D_DIM));
    __syncthreads();

    float p = 0.f;
    for (int i = t; i < K_CODES; i += 256) {
        float pr = (float)hist[i] / (float)N_ROWS;
        p += pr * logf(pr + 1e-10f);
    }
    sdata[t] = p;
    __syncthreads();
    for (int st = 128; st > 0; st >>= 1) {
        if (t < st) sdata[t] += sdata[t + st];
        __syncthreads();
    }
    if (t == 0) out_perp[0] = expf(-sdata[0]);
}

// ---------------------------------------------------------------------------
extern "C" void kernel_launch(void* const* d_in, const int* in_sizes, int n_in,
                              void* d_out, int out_size, void* d_ws, size_t ws_size,
                              hipStream_t stream) {
    const float* lat = (const float*)d_in[0];
    const float* emb = (const float*)d_in[1];
    float* ob = (float*)d_out;

    short* emb_hi = (short*)(ob + 0);
    short* emb_lo = (short*)(ob + 1048576);
    float* pmin   = ob + 2097152;
    float* psec   = ob + 2162688;
    unsigned short* pidx16 = (unsigned short*)(ob + 2228224);  // 32768 floats
    float* e_norm = ob + 2260992;                              // past pidx16 end
    int*   flagcnt  = (int*)(ob + 2265088);
    int*   flaglist = (int*)(ob + 2265089);
    unsigned short* fidx = (unsigned short*)(ob + 16810000);   // 16384 floats
    int*   hist    = (int*)(ob + 16826384);
    float* rowpart = ob + 16830480;

    float* out_q    = ob;
    float* out_loss = ob + 16777216;
    float* out_inds = ob + 16777217;
    float* out_emb  = ob + 16809985;
    float* out_perp = ob + 18907137;

    hipMemsetAsync(flagcnt, 0, sizeof(int), stream);
    hipMemsetAsync(hist, 0, K_CODES * sizeof(int), stream);

    vq_conv_norm<<<dim3(1024), dim3(256), 0, stream>>>(emb, emb_hi, emb_lo, e_norm);

    vq_argmin_mfma<<<dim3(N_ROWS / BROWS, 2), dim3(1024), 0, stream>>>(
        lat, emb_hi, emb_lo, e_norm, pmin, psec, pidx16);

    vq_select<<<dim3(N_ROWS / 256), dim3(256), 0, stream>>>(pmin, psec, pidx16,
                                                            fidx, out_inds,
                                                            flagcnt, flaglist);

    vq_fixrow<<<dim3(512), dim3(FIXT), 0, stream>>>(lat, emb, flagcnt, flaglist,
                                                    fidx, out_inds);

    vq_gather<<<dim3(N_ROWS / 4), dim3(256), 0, stream>>>(lat, emb, fidx, out_q, rowpart, hist);

    vq_finalize<<<dim3(1), dim3(256), 0, stream>>>(rowpart, hist, out_loss, out_perp);

    hipMemcpyAsync(out_emb, emb, (size_t)K_CODES * D_DIM * sizeof(float),
                   hipMemcpyDeviceToDevice, stream);
}